// Round 1
// baseline (3580.098 us; speedup 1.0000x reference)
//
#include <hip/hip_runtime.h>
#include <math.h>

#define D_MODEL 2048
#define NHEADS  16
#define HDIM    128
#define BATCH   2
#define SEQ     2048
#define MTOT    (BATCH*SEQ)   // 4096

// ---------------------------------------------------------------------------
// GEMM: C = A[M,2048] @ W[N,2048]^T + bias  (both row-major, K-contiguous)
// tile 128x128, BK=16, 256 threads, 8x8 micro-tile.
// mode 0: epilogue writes [B,H,S,Dh] (QKV reshape).  mode 1: plain [M,N].
// blockIdx.z selects (W,bias,C) triple so Q,K,V run in one launch.
// ---------------------------------------------------------------------------
__global__ __launch_bounds__(256)
void gemm_kernel(const float* __restrict__ A,
                 const float* W0, const float* W1, const float* W2,
                 const float* b0, const float* b1, const float* b2,
                 float* C0, float* C1, float* C2, int mode)
{
    const int z = blockIdx.z;
    const float* W    = (z == 0) ? W0 : ((z == 1) ? W1 : W2);
    const float* bias = (z == 0) ? b0 : ((z == 1) ? b1 : b2);
    float*       C    = (z == 0) ? C0 : ((z == 1) ? C1 : C2);

    __shared__ float As[16][132];   // [k][m], pad 4 -> 2-way max on writes
    __shared__ float Bs[16][132];   // [k][n]

    const int tid = threadIdx.x;
    const int tx = tid & 15, ty = tid >> 4;
    const int m0 = blockIdx.y * 128;
    const int n0 = blockIdx.x * 128;

    float acc[8][8];
    #pragma unroll
    for (int i = 0; i < 8; ++i)
        #pragma unroll
        for (int j = 0; j < 8; ++j) acc[i][j] = 0.f;

    const int r  = tid >> 2;   // 0..63
    const int c4 = tid & 3;    // 0..3  (float4 column within the 16-wide k slab)

    for (int k0 = 0; k0 < 2048; k0 += 16) {
        __syncthreads();
        #pragma unroll
        for (int half = 0; half < 2; ++half) {
            const int rr = r + half * 64;
            const float4 av = *(const float4*)&A[(size_t)(m0 + rr) * 2048 + k0 + c4 * 4];
            As[c4*4+0][rr] = av.x; As[c4*4+1][rr] = av.y;
            As[c4*4+2][rr] = av.z; As[c4*4+3][rr] = av.w;
            const float4 bv = *(const float4*)&W[(size_t)(n0 + rr) * 2048 + k0 + c4 * 4];
            Bs[c4*4+0][rr] = bv.x; Bs[c4*4+1][rr] = bv.y;
            Bs[c4*4+2][rr] = bv.z; Bs[c4*4+3][rr] = bv.w;
        }
        __syncthreads();
        #pragma unroll
        for (int k = 0; k < 16; ++k) {
            float a[8], b[8];
            *(float4*)&a[0] = *(const float4*)&As[k][ty * 8];
            *(float4*)&a[4] = *(const float4*)&As[k][ty * 8 + 4];
            *(float4*)&b[0] = *(const float4*)&Bs[k][tx * 8];
            *(float4*)&b[4] = *(const float4*)&Bs[k][tx * 8 + 4];
            #pragma unroll
            for (int i = 0; i < 8; ++i)
                #pragma unroll
                for (int j = 0; j < 8; ++j) acc[i][j] += a[i] * b[j];
        }
    }

    float bb[8];
    #pragma unroll
    for (int w = 0; w < 8; ++w) bb[w] = bias[n0 + tx * 8 + w];

    #pragma unroll
    for (int i = 0; i < 8; ++i) {
        const int m = m0 + ty * 8 + i;
        float4 o0, o1;
        o0.x = acc[i][0] + bb[0]; o0.y = acc[i][1] + bb[1];
        o0.z = acc[i][2] + bb[2]; o0.w = acc[i][3] + bb[3];
        o1.x = acc[i][4] + bb[4]; o1.y = acc[i][5] + bb[5];
        o1.z = acc[i][6] + bb[6]; o1.w = acc[i][7] + bb[7];
        if (mode == 0) {
            const int b = m >> 11, s = m & (SEQ - 1);
            const int h = n0 >> 7;           // n0 multiple of 128 => whole block one head
            float* dst = &C[(((size_t)(b * NHEADS + h)) * SEQ + s) * HDIM + tx * 8];
            *(float4*)dst = o0; *(float4*)(dst + 4) = o1;
        } else {
            float* dst = &C[(size_t)m * D_MODEL + n0 + tx * 8];
            *(float4*)dst = o0; *(float4*)(dst + 4) = o1;
        }
    }
}

// ---------------------------------------------------------------------------
// RoPE: precompute cos/sin table [SEQ][64], then apply in-place to Q and K.
// ---------------------------------------------------------------------------
__global__ void rope_table(float* __restrict__ tcos, float* __restrict__ tsin)
{
    const int idx = blockIdx.x * 256 + threadIdx.x;   // SEQ*64
    const int s = idx >> 6, i = idx & 63;
    const float inv = powf(10000.0f, -(float)i / 64.0f);
    const float ang = (float)s * inv;
    tcos[idx] = cosf(ang);
    tsin[idx] = sinf(ang);
}

__global__ void rope_apply(float* __restrict__ Q, float* __restrict__ K,
                           const float* __restrict__ tcos, const float* __restrict__ tsin)
{
    const int idx = blockIdx.x * 256 + threadIdx.x;   // B*H*S*64 per tensor
    float* P = blockIdx.y ? K : Q;
    const int i   = idx & 63;
    const int bhs = idx >> 6;
    const int s   = bhs & (SEQ - 1);
    const size_t base = (size_t)bhs * HDIM;
    const float x1 = P[base + i], x2 = P[base + i + 64];
    const float c  = tcos[(s << 6) + i], sn = tsin[(s << 6) + i];
    P[base + i]      = x1 * c  - x2 * sn;
    P[base + i + 64] = x1 * sn + x2 * c;
}

// ---------------------------------------------------------------------------
// Flash attention (fp32, causal). One block = one (b,h) x 64-row q-tile.
// 256 threads (4 waves). K/Q staged transposed [d][row] with XOR swizzle so
// both staging writes and b128 reads are low-conflict. Online softmax in
// registers, row reductions over the 16-lane tx group via shfl_xor.
// ---------------------------------------------------------------------------
__global__ __launch_bounds__(256)
void flash_attn(const float* __restrict__ Q, const float* __restrict__ K,
                const float* __restrict__ V, float* __restrict__ O)
{
    __shared__ float Qs[128][64];   // [d][q-row], swizzled   32 KB
    __shared__ float Ks[128][64];   // [d][k-row], swizzled   32 KB
    __shared__ float Vs[64][128];   // [k-row][d]             32 KB
    __shared__ float Ps[64][68];    // [k-row][q-row]         17 KB   => 113 KB total

    const int tid = threadIdx.x;
    const int tx = tid & 15, ty = tid >> 4;
    const int bh = blockIdx.y;                       // b*16 + h
    const int bx = blockIdx.x;
    const int qt = (bx & 1) ? (31 - (bx >> 1)) : (bx >> 1);   // balance causal work
    const int q0 = qt * 64;
    const size_t base = (size_t)bh * SEQ * HDIM;
    const float scale = 0.08838834764831845f;        // 1/sqrt(128)

    // ---- stage Q (transposed + swizzled + pre-scaled), once per block ----
    {
        const float* Qg = Q + base + (size_t)q0 * HDIM;
        #pragma unroll
        for (int it = 0; it < 8; ++it) {
            const int f = tid + it * 256;
            const int r = f >> 5, c = f & 31;
            const float4 v = *(const float4*)&Qg[r * HDIM + c * 4];
            const int col = r ^ ((c & 15) << 2);
            Qs[4*c+0][col] = v.x * scale; Qs[4*c+1][col] = v.y * scale;
            Qs[4*c+2][col] = v.z * scale; Qs[4*c+3][col] = v.w * scale;
        }
    }

    float m_run[4], l_run[4], o[4][8];
    #pragma unroll
    for (int i = 0; i < 4; ++i) {
        m_run[i] = -INFINITY; l_run[i] = 0.f;
        #pragma unroll
        for (int w = 0; w < 8; ++w) o[i][w] = 0.f;
    }

    const int nt = qt + 1;
    for (int t = 0; t < nt; ++t) {
        const int k0 = t * 64;
        __syncthreads();   // prev PV done (t=0: Q staging visible)
        // ---- stage K (transposed+swizzled) and V (row-major) ----
        const float* Kg = K + base + (size_t)k0 * HDIM;
        const float* Vg = V + base + (size_t)k0 * HDIM;
        #pragma unroll
        for (int it = 0; it < 8; ++it) {
            const int f = tid + it * 256;
            const int r = f >> 5, c = f & 31;
            const float4 kv = *(const float4*)&Kg[r * HDIM + c * 4];
            const int col = r ^ ((c & 15) << 2);
            Ks[4*c+0][col] = kv.x; Ks[4*c+1][col] = kv.y;
            Ks[4*c+2][col] = kv.z; Ks[4*c+3][col] = kv.w;
            *(float4*)&Vs[r][c * 4] = *(const float4*)&Vg[r * HDIM + c * 4];
        }
        __syncthreads();

        // ---- QK^T: s_acc[4 q][4 k], contraction over d ----
        float s_acc[4][4];
        #pragma unroll
        for (int i = 0; i < 4; ++i)
            #pragma unroll
            for (int j = 0; j < 4; ++j) s_acc[i][j] = 0.f;

        #pragma unroll 2
        for (int d4 = 0; d4 < 128; d4 += 4) {
            const int g  = ((d4 >> 2) & 15) << 2;
            const int qc = (ty * 4) ^ g;
            const int kc = (tx * 4) ^ g;
            #pragma unroll
            for (int dd = 0; dd < 4; ++dd) {
                const float4 qa = *(const float4*)&Qs[d4 + dd][qc];
                const float4 kb = *(const float4*)&Ks[d4 + dd][kc];
                const float qa_[4] = {qa.x, qa.y, qa.z, qa.w};
                const float kb_[4] = {kb.x, kb.y, kb.z, kb.w};
                #pragma unroll
                for (int i = 0; i < 4; ++i)
                    #pragma unroll
                    for (int j = 0; j < 4; ++j) s_acc[i][j] += qa_[i] * kb_[j];
            }
        }

        // ---- causal mask (diagonal tile only: k0 == q0) ----
        if (t == nt - 1) {
            #pragma unroll
            for (int i = 0; i < 4; ++i)
                #pragma unroll
                for (int j = 0; j < 4; ++j)
                    if (tx * 4 + j > ty * 4 + i) s_acc[i][j] = -INFINITY;
        }

        // ---- online softmax (row = ty*4+i, spread over 16 tx lanes) ----
        float p[4][4];
        #pragma unroll
        for (int i = 0; i < 4; ++i) {
            float mt = fmaxf(fmaxf(s_acc[i][0], s_acc[i][1]),
                             fmaxf(s_acc[i][2], s_acc[i][3]));
            #pragma unroll
            for (int msk = 1; msk < 16; msk <<= 1) mt = fmaxf(mt, __shfl_xor(mt, msk));
            const float mn = fmaxf(m_run[i], mt);
            const float alpha = __expf(m_run[i] - mn);
            m_run[i] = mn;
            float rs = 0.f;
            #pragma unroll
            for (int j = 0; j < 4; ++j) { p[i][j] = __expf(s_acc[i][j] - mn); rs += p[i][j]; }
            #pragma unroll
            for (int msk = 1; msk < 16; msk <<= 1) rs += __shfl_xor(rs, msk);
            l_run[i] = l_run[i] * alpha + rs;
            #pragma unroll
            for (int w = 0; w < 8; ++w) o[i][w] *= alpha;
        }

        // ---- write P[k][q] ----
        #pragma unroll
        for (int j = 0; j < 4; ++j) {
            const float4 pw = make_float4(p[0][j], p[1][j], p[2][j], p[3][j]);
            *(float4*)&Ps[tx * 4 + j][ty * 4] = pw;
        }
        __syncthreads();

        // ---- PV: o[4 q][8 d] += P[q][j] * V[j][d] ----
        #pragma unroll 4
        for (int j = 0; j < 64; ++j) {
            const float4 pa = *(const float4*)&Ps[j][ty * 4];
            const float4 v0 = *(const float4*)&Vs[j][tx * 8];
            const float4 v1 = *(const float4*)&Vs[j][tx * 8 + 4];
            const float pa_[4] = {pa.x, pa.y, pa.z, pa.w};
            const float v_[8]  = {v0.x, v0.y, v0.z, v0.w, v1.x, v1.y, v1.z, v1.w};
            #pragma unroll
            for (int i = 0; i < 4; ++i)
                #pragma unroll
                for (int w = 0; w < 8; ++w) o[i][w] += pa_[i] * v_[w];
        }
    }

    // ---- epilogue: normalize and write [B,S,D] so the O-proj GEMM is plain ----
    const int b = bh >> 4, h = bh & 15;
    #pragma unroll
    for (int i = 0; i < 4; ++i) {
        const float inv = 1.f / l_run[i];
        const int s = q0 + ty * 4 + i;
        float* dst = O + ((size_t)b * SEQ + s) * D_MODEL + h * HDIM + tx * 8;
        float4 o0, o1;
        o0.x = o[i][0]*inv; o0.y = o[i][1]*inv; o0.z = o[i][2]*inv; o0.w = o[i][3]*inv;
        o1.x = o[i][4]*inv; o1.y = o[i][5]*inv; o1.z = o[i][6]*inv; o1.w = o[i][7]*inv;
        *(float4*)dst = o0; *(float4*)(dst + 4) = o1;
    }
}

// ---------------------------------------------------------------------------
extern "C" void kernel_launch(void* const* d_in, const int* in_sizes, int n_in,
                              void* d_out, int out_size, void* d_ws, size_t ws_size,
                              hipStream_t stream)
{
    const float* x  = (const float*)d_in[0];
    // d_in[1] = mask (tril) -- causal handled analytically
    const float* Wq = (const float*)d_in[2];
    const float* bq = (const float*)d_in[3];
    const float* Wk = (const float*)d_in[4];
    const float* bk = (const float*)d_in[5];
    const float* Wv = (const float*)d_in[6];
    const float* bv = (const float*)d_in[7];
    const float* Wo = (const float*)d_in[8];
    const float* bo = (const float*)d_in[9];
    float* out = (float*)d_out;

    float* ws = (float*)d_ws;
    const size_t TEN = (size_t)BATCH * NHEADS * SEQ * HDIM;   // 8388608
    float* Qr = ws;             // [B,H,S,Dh]
    float* Kr = Qr + TEN;
    float* Vr = Kr + TEN;
    float* An = Vr + TEN;       // attention out, [B,S,D]
    float* tc = An + TEN;       // cos table [SEQ][64]
    float* tsn = tc + (size_t)SEQ * 64;

    rope_table<<<dim3((SEQ * 64) / 256), 256, 0, stream>>>(tc, tsn);

    gemm_kernel<<<dim3(D_MODEL / 128, MTOT / 128, 3), 256, 0, stream>>>(
        x, Wq, Wk, Wv, bq, bk, bv, Qr, Kr, Vr, 0);

    rope_apply<<<dim3((BATCH * NHEADS * SEQ * 64) / 256, 2), 256, 0, stream>>>(
        Qr, Kr, tc, tsn);

    flash_attn<<<dim3(SEQ / 64, BATCH * NHEADS), 256, 0, stream>>>(Qr, Kr, Vr, An);

    gemm_kernel<<<dim3(D_MODEL / 128, MTOT / 128, 1), 256, 0, stream>>>(
        An, Wo, Wo, Wo, bo, bo, bo, out, out, out, 1);
}

// Round 2
// 1557.272 us; speedup vs baseline: 2.2990x; 2.2990x over previous
//
#include <hip/hip_runtime.h>
#include <math.h>

#define D_MODEL 2048
#define NHEADS  16
#define HDIM    128
#define BATCH   2
#define SEQ     2048
#define MTOT    (BATCH*SEQ)   // 4096

typedef unsigned short u16;
typedef unsigned int   u32;
typedef __attribute__((ext_vector_type(8))) short  short8;
typedef __attribute__((ext_vector_type(8))) u16    ushort8;
typedef __attribute__((ext_vector_type(4))) float  floatx4;

__device__ __forceinline__ u16 f2b(float f) {          // fp32 -> bf16 RNE
    u32 u = __float_as_uint(f);
    return (u16)((u + 0x7fffu + ((u >> 16) & 1u)) >> 16);
}
__device__ __forceinline__ float b2f(u16 b) {          // bf16 -> fp32 exact
    return __uint_as_float(((u32)b) << 16);
}
__device__ __forceinline__ void async16(void* lds, const void* g) {
    __builtin_amdgcn_global_load_lds(
        (const __attribute__((address_space(1))) u32*)g,
        (__attribute__((address_space(3))) u32*)lds, 16, 0, 0);
}

// ---------------------------------------------------------------------------
// fp32 -> bf16 conversion for x and the 4 weight matrices.
// 256 thr x 8 elems per block. Segments: x = 4096 blocks, each W = 2048.
// ---------------------------------------------------------------------------
__global__ __launch_bounds__(256)
void f2b_kernel(const float* __restrict__ x,
                const float* __restrict__ wq, const float* __restrict__ wk,
                const float* __restrict__ wv, const float* __restrict__ wo,
                u16* __restrict__ xb, u16* __restrict__ wqb, u16* __restrict__ wkb,
                u16* __restrict__ wvb, u16* __restrict__ wob)
{
    const int bid = blockIdx.x;
    const float* src; u16* dst; int lb;
    if (bid < 4096) { src = x; dst = xb; lb = bid; }
    else {
        const int t = (bid - 4096) >> 11;
        lb = (bid - 4096) & 2047;
        src = (t == 0) ? wq : (t == 1) ? wk : (t == 2) ? wv : wo;
        dst = (t == 0) ? wqb : (t == 1) ? wkb : (t == 2) ? wvb : wob;
    }
    const size_t e = ((size_t)lb * 256 + threadIdx.x) * 8;
    const float4 a = *(const float4*)&src[e];
    const float4 b = *(const float4*)&src[e + 4];
    union { u16 u[8]; uint4 v; } o;
    o.u[0] = f2b(a.x); o.u[1] = f2b(a.y); o.u[2] = f2b(a.z); o.u[3] = f2b(a.w);
    o.u[4] = f2b(b.x); o.u[5] = f2b(b.y); o.u[6] = f2b(b.z); o.u[7] = f2b(b.w);
    *(uint4*)&dst[e] = o.v;
}

// ---------------------------------------------------------------------------
// bf16 MFMA GEMM: C = A[M,2048] @ W[N,2048]^T + bias (fp32 accum).
// m97 structure: 128x128 tile, BK=32, 4 waves (2x2 of 64x64), 4x4 16x16x32
// frags, global_load_lds width 16, single-buffer 2-barrier K-loop.
// mode 0: write bf16 QKV [B,H,S,Dh]. mode 1: write fp32 [M,N].
// ---------------------------------------------------------------------------
__global__ __launch_bounds__(256)
void gemm_bf16(const u16* __restrict__ A,
               const u16* W0, const u16* W1, const u16* W2,
               const float* b0, const float* b1, const float* b2,
               void* C0, void* C1, void* C2, int mode)
{
    __shared__ __align__(16) u16 As[128 * 32];
    __shared__ __align__(16) u16 Bs[128 * 32];

    const int z = blockIdx.z;
    const u16*   W    = (z == 0) ? W0 : (z == 1) ? W1 : W2;
    const float* bias = (z == 0) ? b0 : (z == 1) ? b1 : b2;
    void*        C    = (z == 0) ? C0 : (z == 1) ? C1 : C2;

    const int tid  = threadIdx.x;
    const int lane = tid & 63;
    const int wv   = tid >> 6;          // wave 0..3
    const int wr   = wv >> 1, wc = wv & 1;
    const int m0 = blockIdx.y * 128, n0 = blockIdx.x * 128;

    floatx4 acc[4][4];
    #pragma unroll
    for (int i = 0; i < 4; ++i)
        #pragma unroll
        for (int j = 0; j < 4; ++j) acc[i][j] = (floatx4){0.f, 0.f, 0.f, 0.f};

    // staging slots: f in [0,512), 16B each; row = f>>2, byte-in-row = (f&3)*16
    const int f0 = tid, f1 = tid + 256;
    const char* Ag = (const char*)(A + (size_t)m0 * 2048);
    const char* Wg = (const char*)(W + (size_t)n0 * 2048);
    const size_t a0 = (size_t)(f0 >> 2) * 4096 + (f0 & 3) * 16;
    const size_t a1 = (size_t)(f1 >> 2) * 4096 + (f1 & 3) * 16;

    const int lrow = lane & 15, lk = (lane >> 4) * 8;

    for (int k0 = 0; k0 < 2048; k0 += 32) {
        __syncthreads();
        const size_t kb = (size_t)k0 * 2;
        async16(&As[f0 * 8], Ag + a0 + kb);
        async16(&As[f1 * 8], Ag + a1 + kb);
        async16(&Bs[f0 * 8], Wg + a0 + kb);
        async16(&Bs[f1 * 8], Wg + a1 + kb);
        __syncthreads();

        short8 af[4], bf[4];
        #pragma unroll
        for (int i = 0; i < 4; ++i)
            af[i] = *(const short8*)&As[(wr * 64 + i * 16 + lrow) * 32 + lk];
        #pragma unroll
        for (int j = 0; j < 4; ++j)
            bf[j] = *(const short8*)&Bs[(wc * 64 + j * 16 + lrow) * 32 + lk];
        #pragma unroll
        for (int i = 0; i < 4; ++i)
            #pragma unroll
            for (int j = 0; j < 4; ++j)
                acc[i][j] = __builtin_amdgcn_mfma_f32_16x16x32_bf16(af[i], bf[j], acc[i][j], 0, 0, 0);
    }

    float bb[4];
    #pragma unroll
    for (int j = 0; j < 4; ++j) bb[j] = bias[n0 + wc * 64 + j * 16 + lrow];

    #pragma unroll
    for (int i = 0; i < 4; ++i) {
        #pragma unroll
        for (int j = 0; j < 4; ++j) {
            const int col = n0 + wc * 64 + j * 16 + lrow;   // C/D: col = lane&15
            #pragma unroll
            for (int q = 0; q < 4; ++q) {
                const int row = m0 + wr * 64 + i * 16 + (lane >> 4) * 4 + q;
                const float val = acc[i][j][q] + bb[j];
                if (mode == 0) {
                    const int b = row >> 11, s = row & (SEQ - 1);
                    const int h = col >> 7,  d = col & 127;
                    ((u16*)C)[(((size_t)(b * NHEADS + h)) * SEQ + s) * HDIM + d] = f2b(val);
                } else {
                    ((float*)C)[(size_t)row * D_MODEL + col] = val;
                }
            }
        }
    }
}

// ---------------------------------------------------------------------------
// RoPE: cos/sin table [SEQ][64], then apply in-place to bf16 Q and K.
// ---------------------------------------------------------------------------
__global__ void rope_table(float* __restrict__ tcos, float* __restrict__ tsin)
{
    const int idx = blockIdx.x * 256 + threadIdx.x;   // SEQ*64
    const int s = idx >> 6, i = idx & 63;
    const float inv = powf(10000.0f, -(float)i / 64.0f);
    const float ang = (float)s * inv;
    tcos[idx] = cosf(ang);
    tsin[idx] = sinf(ang);
}

__global__ void rope_apply(u16* __restrict__ Q, u16* __restrict__ K,
                           const float* __restrict__ tcos, const float* __restrict__ tsin)
{
    const int idx = blockIdx.x * 256 + threadIdx.x;   // B*H*S*64 per tensor
    u16* P = blockIdx.y ? K : Q;
    const int i   = idx & 63;
    const int bhs = idx >> 6;
    const int s   = bhs & (SEQ - 1);
    const size_t base = (size_t)bhs * HDIM;
    const float x1 = b2f(P[base + i]), x2 = b2f(P[base + i + 64]);
    const float c  = tcos[(s << 6) + i], sn = tsin[(s << 6) + i];
    P[base + i]      = f2b(x1 * c  - x2 * sn);
    P[base + i + 64] = f2b(x1 * sn + x2 * c);
}

// ---------------------------------------------------------------------------
// Flash attention (fp32 compute, bf16 in/out, causal).
// One block = one (b,h) x 64-row q-tile. Unchanged math from round 1.
// ---------------------------------------------------------------------------
__global__ __launch_bounds__(256)
void flash_attn(const u16* __restrict__ Q, const u16* __restrict__ K,
                const u16* __restrict__ V, u16* __restrict__ O)
{
    __shared__ float Qs[128][64];   // [d][q-row], swizzled   32 KB
    __shared__ float Ks[128][64];   // [d][k-row], swizzled   32 KB
    __shared__ float Vs[64][128];   // [k-row][d]             32 KB
    __shared__ float Ps[64][68];    // [k-row][q-row]         17 KB

    const int tid = threadIdx.x;
    const int tx = tid & 15, ty = tid >> 4;
    const int bh = blockIdx.y;
    const int bx = blockIdx.x;
    const int qt = (bx & 1) ? (31 - (bx >> 1)) : (bx >> 1);
    const int q0 = qt * 64;
    const size_t base = (size_t)bh * SEQ * HDIM;
    const float scale = 0.08838834764831845f;   // 1/sqrt(128)

    // ---- stage Q (transposed + swizzled + pre-scaled) ----
    {
        const u16* Qg = Q + base + (size_t)q0 * HDIM;
        #pragma unroll
        for (int it = 0; it < 4; ++it) {
            const int f = tid + it * 256;         // 0..1023
            const int r = f >> 4, c8 = f & 15;
            const ushort8 v = *(const ushort8*)&Qg[(size_t)r * HDIM + c8 * 8];
            #pragma unroll
            for (int dd = 0; dd < 8; ++dd) {
                const int d = c8 * 8 + dd;
                const int col = r ^ (((d >> 2) & 15) << 2);
                Qs[d][col] = b2f(v[dd]) * scale;
            }
        }
    }

    float m_run[4], l_run[4], o[4][8];
    #pragma unroll
    for (int i = 0; i < 4; ++i) {
        m_run[i] = -INFINITY; l_run[i] = 0.f;
        #pragma unroll
        for (int w = 0; w < 8; ++w) o[i][w] = 0.f;
    }

    const int nt = qt + 1;
    for (int t = 0; t < nt; ++t) {
        const int k0 = t * 64;
        __syncthreads();
        const u16* Kg = K + base + (size_t)k0 * HDIM;
        const u16* Vg = V + base + (size_t)k0 * HDIM;
        #pragma unroll
        for (int it = 0; it < 4; ++it) {
            const int f = tid + it * 256;
            const int r = f >> 4, c8 = f & 15;
            const ushort8 kv = *(const ushort8*)&Kg[(size_t)r * HDIM + c8 * 8];
            const ushort8 vv = *(const ushort8*)&Vg[(size_t)r * HDIM + c8 * 8];
            #pragma unroll
            for (int dd = 0; dd < 8; ++dd) {
                const int d = c8 * 8 + dd;
                Ks[d][r ^ (((d >> 2) & 15) << 2)] = b2f(kv[dd]);
                Vs[r][d] = b2f(vv[dd]);
            }
        }
        __syncthreads();

        float s_acc[4][4];
        #pragma unroll
        for (int i = 0; i < 4; ++i)
            #pragma unroll
            for (int j = 0; j < 4; ++j) s_acc[i][j] = 0.f;

        #pragma unroll 2
        for (int d4 = 0; d4 < 128; d4 += 4) {
            const int g  = ((d4 >> 2) & 15) << 2;
            const int qc = (ty * 4) ^ g;
            const int kc = (tx * 4) ^ g;
            #pragma unroll
            for (int dd = 0; dd < 4; ++dd) {
                const float4 qa = *(const float4*)&Qs[d4 + dd][qc];
                const float4 kb = *(const float4*)&Ks[d4 + dd][kc];
                const float qa_[4] = {qa.x, qa.y, qa.z, qa.w};
                const float kb_[4] = {kb.x, kb.y, kb.z, kb.w};
                #pragma unroll
                for (int i = 0; i < 4; ++i)
                    #pragma unroll
                    for (int j = 0; j < 4; ++j) s_acc[i][j] += qa_[i] * kb_[j];
            }
        }

        if (t == nt - 1) {
            #pragma unroll
            for (int i = 0; i < 4; ++i)
                #pragma unroll
                for (int j = 0; j < 4; ++j)
                    if (tx * 4 + j > ty * 4 + i) s_acc[i][j] = -INFINITY;
        }

        float p[4][4];
        #pragma unroll
        for (int i = 0; i < 4; ++i) {
            float mt = fmaxf(fmaxf(s_acc[i][0], s_acc[i][1]),
                             fmaxf(s_acc[i][2], s_acc[i][3]));
            #pragma unroll
            for (int msk = 1; msk < 16; msk <<= 1) mt = fmaxf(mt, __shfl_xor(mt, msk));
            const float mn = fmaxf(m_run[i], mt);
            const float alpha = __expf(m_run[i] - mn);
            m_run[i] = mn;
            float rs = 0.f;
            #pragma unroll
            for (int j = 0; j < 4; ++j) { p[i][j] = __expf(s_acc[i][j] - mn); rs += p[i][j]; }
            #pragma unroll
            for (int msk = 1; msk < 16; msk <<= 1) rs += __shfl_xor(rs, msk);
            l_run[i] = l_run[i] * alpha + rs;
            #pragma unroll
            for (int w = 0; w < 8; ++w) o[i][w] *= alpha;
        }

        #pragma unroll
        for (int j = 0; j < 4; ++j) {
            const float4 pw = make_float4(p[0][j], p[1][j], p[2][j], p[3][j]);
            *(float4*)&Ps[tx * 4 + j][ty * 4] = pw;
        }
        __syncthreads();

        #pragma unroll 4
        for (int j = 0; j < 64; ++j) {
            const float4 pa = *(const float4*)&Ps[j][ty * 4];
            const float4 v0 = *(const float4*)&Vs[j][tx * 8];
            const float4 v1 = *(const float4*)&Vs[j][tx * 8 + 4];
            const float pa_[4] = {pa.x, pa.y, pa.z, pa.w};
            const float v_[8]  = {v0.x, v0.y, v0.z, v0.w, v1.x, v1.y, v1.z, v1.w};
            #pragma unroll
            for (int i = 0; i < 4; ++i)
                #pragma unroll
                for (int w = 0; w < 8; ++w) o[i][w] += pa_[i] * v_[w];
        }
    }

    // ---- epilogue: normalize, write bf16 [B,S,D] ----
    const int b = bh >> 4, h = bh & 15;
    #pragma unroll
    for (int i = 0; i < 4; ++i) {
        const float inv = 1.f / l_run[i];
        const int s = q0 + ty * 4 + i;
        u16* dst = O + ((size_t)b * SEQ + s) * D_MODEL + h * HDIM + tx * 8;
        ushort8 ov;
        #pragma unroll
        for (int w = 0; w < 8; ++w) ov[w] = f2b(o[i][w] * inv);
        *(ushort8*)dst = ov;
    }
}

// ---------------------------------------------------------------------------
extern "C" void kernel_launch(void* const* d_in, const int* in_sizes, int n_in,
                              void* d_out, int out_size, void* d_ws, size_t ws_size,
                              hipStream_t stream)
{
    const float* x  = (const float*)d_in[0];
    const float* Wq = (const float*)d_in[2];
    const float* bq = (const float*)d_in[3];
    const float* Wk = (const float*)d_in[4];
    const float* bk = (const float*)d_in[5];
    const float* Wv = (const float*)d_in[6];
    const float* bv = (const float*)d_in[7];
    const float* Wo = (const float*)d_in[8];
    const float* bo = (const float*)d_in[9];
    float* out = (float*)d_out;

    const size_t TEN = (size_t)MTOT * D_MODEL;        // 8,388,608 elems
    const size_t WEL = (size_t)D_MODEL * D_MODEL;     // 4,194,304 elems
    char* p = (char*)d_ws;
    u16* xb  = (u16*)p; p += TEN * 2;
    u16* wqb = (u16*)p; p += WEL * 2;
    u16* wkb = (u16*)p; p += WEL * 2;
    u16* wvb = (u16*)p; p += WEL * 2;
    u16* wob = (u16*)p; p += WEL * 2;
    u16* Qb  = (u16*)p; p += TEN * 2;
    u16* Kb  = (u16*)p; p += TEN * 2;
    u16* Vb  = (u16*)p; p += TEN * 2;
    u16* An  = (u16*)p; p += TEN * 2;
    float* tc = (float*)p; p += (size_t)SEQ * 64 * 4;
    float* ts = (float*)p;

    f2b_kernel<<<dim3(12288), 256, 0, stream>>>(x, Wq, Wk, Wv, Wo,
                                                xb, wqb, wkb, wvb, wob);
    rope_table<<<dim3(512), 256, 0, stream>>>(tc, ts);
    gemm_bf16<<<dim3(16, 32, 3), 256, 0, stream>>>(xb, wqb, wkb, wvb,
                                                   bq, bk, bv, Qb, Kb, Vb, 0);
    rope_apply<<<dim3(16384, 2), 256, 0, stream>>>(Qb, Kb, tc, ts);
    flash_attn<<<dim3(32, 32), 256, 0, stream>>>(Qb, Kb, Vb, An);
    gemm_bf16<<<dim3(16, 32, 1), 256, 0, stream>>>(An, wob, wob, wob,
                                                   bo, bo, bo, out, out, out, 1);
}

// Round 3
// 671.453 us; speedup vs baseline: 5.3319x; 2.3193x over previous
//
#include <hip/hip_runtime.h>
#include <math.h>

#define D_MODEL 2048
#define NHEADS  16
#define HDIM    128
#define BATCH   2
#define SEQ     2048
#define MTOT    (BATCH*SEQ)   // 4096

typedef unsigned short u16;
typedef unsigned int   u32;
typedef __attribute__((ext_vector_type(8))) short  short8;
typedef __attribute__((ext_vector_type(8))) u16    ushort8;
typedef __attribute__((ext_vector_type(4))) u16    us4;
typedef __attribute__((ext_vector_type(4))) float  floatx4;

__device__ __forceinline__ u16 f2b(float f) {          // fp32 -> bf16 RNE
    u32 u = __float_as_uint(f);
    return (u16)((u + 0x7fffu + ((u >> 16) & 1u)) >> 16);
}
__device__ __forceinline__ float b2f(u16 b) {          // bf16 -> fp32 exact
    return __uint_as_float(((u32)b) << 16);
}
__device__ __forceinline__ void async16(void* lds, const void* g) {
    __builtin_amdgcn_global_load_lds(
        (const __attribute__((address_space(1))) u32*)g,
        (__attribute__((address_space(3))) u32*)lds, 16, 0, 0);
}

// ---------------------------------------------------------------------------
// fp32 -> bf16 conversion for x and the 4 weight matrices.
// ---------------------------------------------------------------------------
__global__ __launch_bounds__(256)
void f2b_kernel(const float* __restrict__ x,
                const float* __restrict__ wq, const float* __restrict__ wk,
                const float* __restrict__ wv, const float* __restrict__ wo,
                u16* __restrict__ xb, u16* __restrict__ wqb, u16* __restrict__ wkb,
                u16* __restrict__ wvb, u16* __restrict__ wob)
{
    const int bid = blockIdx.x;
    const float* src; u16* dst; int lb;
    if (bid < 4096) { src = x; dst = xb; lb = bid; }
    else {
        const int t = (bid - 4096) >> 11;
        lb = (bid - 4096) & 2047;
        src = (t == 0) ? wq : (t == 1) ? wk : (t == 2) ? wv : wo;
        dst = (t == 0) ? wqb : (t == 1) ? wkb : (t == 2) ? wvb : wob;
    }
    const size_t e = ((size_t)lb * 256 + threadIdx.x) * 8;
    const float4 a = *(const float4*)&src[e];
    const float4 b = *(const float4*)&src[e + 4];
    union { u16 u[8]; uint4 v; } o;
    o.u[0] = f2b(a.x); o.u[1] = f2b(a.y); o.u[2] = f2b(a.z); o.u[3] = f2b(a.w);
    o.u[4] = f2b(b.x); o.u[5] = f2b(b.y); o.u[6] = f2b(b.z); o.u[7] = f2b(b.w);
    *(uint4*)&dst[e] = o.v;
}

// ---------------------------------------------------------------------------
// bf16 MFMA GEMM: C = A[M,2048] @ W[N,2048]^T + bias (fp32 accum).
// mode 0: z=0/1 write bf16 [B,H,S,Dh]; z=2 writes bf16 V TRANSPOSED [B,H,Dh,S].
// mode 1: plain fp32 [M,N].
// ---------------------------------------------------------------------------
__global__ __launch_bounds__(256)
void gemm_bf16(const u16* __restrict__ A,
               const u16* W0, const u16* W1, const u16* W2,
               const float* b0, const float* b1, const float* b2,
               void* C0, void* C1, void* C2, int mode)
{
    __shared__ __align__(16) u16 As[128 * 32];
    __shared__ __align__(16) u16 Bs[128 * 32];

    const int z = blockIdx.z;
    const u16*   W    = (z == 0) ? W0 : (z == 1) ? W1 : W2;
    const float* bias = (z == 0) ? b0 : (z == 1) ? b1 : b2;
    void*        C    = (z == 0) ? C0 : (z == 1) ? C1 : C2;

    const int tid  = threadIdx.x;
    const int lane = tid & 63;
    const int wv   = tid >> 6;
    const int wr   = wv >> 1, wc = wv & 1;
    const int m0 = blockIdx.y * 128, n0 = blockIdx.x * 128;

    floatx4 acc[4][4];
    #pragma unroll
    for (int i = 0; i < 4; ++i)
        #pragma unroll
        for (int j = 0; j < 4; ++j) acc[i][j] = (floatx4){0.f, 0.f, 0.f, 0.f};

    const int f0 = tid, f1 = tid + 256;
    const char* Ag = (const char*)(A + (size_t)m0 * 2048);
    const char* Wg = (const char*)(W + (size_t)n0 * 2048);
    const size_t a0 = (size_t)(f0 >> 2) * 4096 + (f0 & 3) * 16;
    const size_t a1 = (size_t)(f1 >> 2) * 4096 + (f1 & 3) * 16;

    const int lrow = lane & 15, lk = (lane >> 4) * 8;

    for (int k0 = 0; k0 < 2048; k0 += 32) {
        __syncthreads();
        const size_t kb = (size_t)k0 * 2;
        async16(&As[f0 * 8], Ag + a0 + kb);
        async16(&As[f1 * 8], Ag + a1 + kb);
        async16(&Bs[f0 * 8], Wg + a0 + kb);
        async16(&Bs[f1 * 8], Wg + a1 + kb);
        __syncthreads();

        short8 af[4], bf[4];
        #pragma unroll
        for (int i = 0; i < 4; ++i)
            af[i] = *(const short8*)&As[(wr * 64 + i * 16 + lrow) * 32 + lk];
        #pragma unroll
        for (int j = 0; j < 4; ++j)
            bf[j] = *(const short8*)&Bs[(wc * 64 + j * 16 + lrow) * 32 + lk];
        #pragma unroll
        for (int i = 0; i < 4; ++i)
            #pragma unroll
            for (int j = 0; j < 4; ++j)
                acc[i][j] = __builtin_amdgcn_mfma_f32_16x16x32_bf16(af[i], bf[j], acc[i][j], 0, 0, 0);
    }

    float bb[4];
    #pragma unroll
    for (int j = 0; j < 4; ++j) bb[j] = bias[n0 + wc * 64 + j * 16 + lrow];

    #pragma unroll
    for (int i = 0; i < 4; ++i) {
        #pragma unroll
        for (int j = 0; j < 4; ++j) {
            const int col  = n0 + wc * 64 + j * 16 + lrow;
            const int row0 = m0 + wr * 64 + i * 16 + (lane >> 4) * 4;
            if (mode == 0) {
                const int b = row0 >> 11, s = row0 & (SEQ - 1);
                const int h = col >> 7,  d = col & 127;
                if (z == 2) {
                    // V transposed: [B,H,Dh,S], 4 consecutive s -> one 8B store
                    us4 pk;
                    #pragma unroll
                    for (int q = 0; q < 4; ++q) pk[q] = f2b(acc[i][j][q] + bb[j]);
                    *(us4*)&((u16*)C)[(((size_t)(b * NHEADS + h)) * HDIM + d) * SEQ + s] = pk;
                } else {
                    #pragma unroll
                    for (int q = 0; q < 4; ++q)
                        ((u16*)C)[(((size_t)(b * NHEADS + h)) * SEQ + s + q) * HDIM + d]
                            = f2b(acc[i][j][q] + bb[j]);
                }
            } else {
                #pragma unroll
                for (int q = 0; q < 4; ++q)
                    ((float*)C)[(size_t)(row0 + q) * D_MODEL + col] = acc[i][j][q] + bb[j];
            }
        }
    }
}

// ---------------------------------------------------------------------------
// RoPE table + apply. Q is additionally pre-scaled by 1/sqrt(HDIM).
// ---------------------------------------------------------------------------
__global__ void rope_table(float* __restrict__ tcos, float* __restrict__ tsin)
{
    const int idx = blockIdx.x * 256 + threadIdx.x;   // SEQ*64
    const int s = idx >> 6, i = idx & 63;
    const float inv = powf(10000.0f, -(float)i / 64.0f);
    const float ang = (float)s * inv;
    tcos[idx] = cosf(ang);
    tsin[idx] = sinf(ang);
}

__global__ void rope_apply(u16* __restrict__ Q, u16* __restrict__ K,
                           const float* __restrict__ tcos, const float* __restrict__ tsin)
{
    const int idx = blockIdx.x * 256 + threadIdx.x;
    u16* P = blockIdx.y ? K : Q;
    const float sc = blockIdx.y ? 1.0f : 0.08838834764831845f;  // 1/sqrt(128)
    const int i   = idx & 63;
    const int bhs = idx >> 6;
    const int s   = bhs & (SEQ - 1);
    const size_t base = (size_t)bhs * HDIM;
    const float x1 = b2f(P[base + i]), x2 = b2f(P[base + i + 64]);
    const float c  = tcos[(s << 6) + i], sn = tsin[(s << 6) + i];
    P[base + i]      = f2b((x1 * c  - x2 * sn) * sc);
    P[base + i + 64] = f2b((x1 * sn + x2 * c) * sc);
}

// ---------------------------------------------------------------------------
// MFMA flash attention (bf16 MFMA, fp32 softmax, causal).
// Block = (b,h) x 64 q-rows, 4 waves x 16 q-rows. K tiles [64][128] and
// Vt tiles [128][64] staged via global_load_lds with inverse-swizzled source;
// all LDS reads use byte ^= ((row&7)<<4) -> <=2-way conflicts.
// ---------------------------------------------------------------------------
__global__ __launch_bounds__(256)
void flash_attn_mfma(const u16* __restrict__ Q, const u16* __restrict__ K,
                     const u16* __restrict__ Vt, u16* __restrict__ O)
{
    __shared__ __align__(16) u16 Ks[64 * 128];   // 16 KB, rows of 256B (16 chunks)
    __shared__ __align__(16) u16 Vs[128 * 64];   // 16 KB, rows of 128B (8 chunks)
    __shared__ __align__(16) u16 Ps[64 * 64];    //  8 KB, rows of 128B (8 chunks)

    const int tid = threadIdx.x, lane = tid & 63, w = tid >> 6;
    const int l15 = lane & 15, l4 = lane >> 4;
    const int bh = blockIdx.y, bx = blockIdx.x;
    const int qt = (bx & 1) ? (31 - (bx >> 1)) : (bx >> 1);
    const int q0 = qt * 64;
    const size_t baseQK = (size_t)bh * SEQ * HDIM;
    const size_t baseV  = (size_t)bh * HDIM * SEQ;

    // Q fragments straight from global (Q already rope'd + pre-scaled)
    short8 qf[4];
    {
        const u16* Qg = Q + baseQK + (size_t)(q0 + w * 16 + l15) * HDIM;
        #pragma unroll
        for (int kk = 0; kk < 4; ++kk) qf[kk] = *(const short8*)&Qg[kk * 32 + l4 * 8];
    }

    floatx4 o_acc[8];
    #pragma unroll
    for (int j2 = 0; j2 < 8; ++j2) o_acc[j2] = (floatx4){0.f, 0.f, 0.f, 0.f};
    float m_run[4], l_run[4];
    #pragma unroll
    for (int r = 0; r < 4; ++r) { m_run[r] = -INFINITY; l_run[r] = 0.f; }

    const int nt = qt + 1;
    for (int t = 0; t < nt; ++t) {
        const int k0 = t * 64;
        __syncthreads();
        // ---- stage K tile (64x128) ----
        {
            const u16* Kg = K + baseQK + (size_t)k0 * HDIM;
            #pragma unroll
            for (int p = 0; p < 4; ++p) {
                const int idx = p * 256 + tid;
                const int r = idx >> 4, c = idx & 15;
                const int src = (c & 8) | ((c & 7) ^ (r & 7));
                async16(&Ks[idx * 8], Kg + r * HDIM + src * 8);
            }
        }
        // ---- stage Vt tile (128x64) ----
        {
            const u16* Vg = Vt + baseV + k0;
            #pragma unroll
            for (int p = 0; p < 4; ++p) {
                const int idx = p * 256 + tid;
                const int r = idx >> 3, c = idx & 7;
                const int src = c ^ (r & 7);
                async16(&Vs[idx * 8], Vg + (size_t)r * SEQ + src * 8);
            }
        }
        __syncthreads();

        // ---- QK^T: wave's 16 q x 64 kv ----
        floatx4 s[4];
        #pragma unroll
        for (int j = 0; j < 4; ++j) s[j] = (floatx4){0.f, 0.f, 0.f, 0.f};
        #pragma unroll
        for (int j = 0; j < 4; ++j) {
            const int row = j * 16 + l15;
            #pragma unroll
            for (int kk = 0; kk < 4; ++kk) {
                const int x = kk * 4 + l4;
                const int ch = (x & 8) | ((x & 7) ^ (row & 7));
                const short8 kf = *(const short8*)&Ks[row * 128 + ch * 8];
                s[j] = __builtin_amdgcn_mfma_f32_16x16x32_bf16(qf[kk], kf, s[j], 0, 0, 0);
            }
        }

        // ---- causal mask on diagonal tile ----
        if (t == nt - 1) {
            #pragma unroll
            for (int j = 0; j < 4; ++j)
                #pragma unroll
                for (int r = 0; r < 4; ++r)
                    if (j * 16 + l15 > w * 16 + l4 * 4 + r) s[j][r] = -INFINITY;
        }

        // ---- online softmax (rows spread over 16 lanes) ----
        float p[4][4];
        #pragma unroll
        for (int r = 0; r < 4; ++r) {
            float mt = fmaxf(fmaxf(s[0][r], s[1][r]), fmaxf(s[2][r], s[3][r]));
            #pragma unroll
            for (int msk = 1; msk < 16; msk <<= 1) mt = fmaxf(mt, __shfl_xor(mt, msk));
            const float mn = fmaxf(m_run[r], mt);
            const float al = __expf(m_run[r] - mn);
            m_run[r] = mn;
            float rs = 0.f;
            #pragma unroll
            for (int j = 0; j < 4; ++j) { p[j][r] = __expf(s[j][r] - mn); rs += p[j][r]; }
            #pragma unroll
            for (int msk = 1; msk < 16; msk <<= 1) rs += __shfl_xor(rs, msk);
            l_run[r] = l_run[r] * al + rs;
            #pragma unroll
            for (int j2 = 0; j2 < 8; ++j2) o_acc[j2][r] *= al;
        }

        // ---- write P (bf16) to this wave's private 16-row stripe ----
        #pragma unroll
        for (int j = 0; j < 4; ++j)
            #pragma unroll
            for (int r = 0; r < 4; ++r) {
                const int row  = w * 16 + l4 * 4 + r;
                const int byte = (j * 32 + l15 * 2) ^ ((row & 7) << 4);
                Ps[row * 64 + (byte >> 1)] = f2b(p[j][r]);
            }

        // ---- PV: o[16 q][128 d] += P[16][64] * Vt[128][64]^T ----
        #pragma unroll
        for (int kb = 0; kb < 2; ++kb) {
            const int qrow = w * 16 + l15;
            const int pch  = (kb * 4 + l4) ^ (qrow & 7);
            const short8 pf = *(const short8*)&Ps[qrow * 64 + pch * 8];
            #pragma unroll
            for (int j2 = 0; j2 < 8; ++j2) {
                const int vrow = j2 * 16 + l15;
                const int vch  = (kb * 4 + l4) ^ (vrow & 7);
                const short8 vf = *(const short8*)&Vs[vrow * 64 + vch * 8];
                o_acc[j2] = __builtin_amdgcn_mfma_f32_16x16x32_bf16(pf, vf, o_acc[j2], 0, 0, 0);
            }
        }
    }

    // ---- epilogue: normalize, write bf16 [B,S,D] ----
    const int b = bh >> 4, h = bh & 15;
    #pragma unroll
    for (int r = 0; r < 4; ++r) {
        const float inv = 1.f / l_run[r];
        const int s_ = q0 + w * 16 + l4 * 4 + r;
        u16* dst = O + ((size_t)b * SEQ + s_) * D_MODEL + h * HDIM;
        #pragma unroll
        for (int j2 = 0; j2 < 8; ++j2)
            dst[j2 * 16 + l15] = f2b(o_acc[j2][r] * inv);
    }
}

// ---------------------------------------------------------------------------
extern "C" void kernel_launch(void* const* d_in, const int* in_sizes, int n_in,
                              void* d_out, int out_size, void* d_ws, size_t ws_size,
                              hipStream_t stream)
{
    const float* x  = (const float*)d_in[0];
    const float* Wq = (const float*)d_in[2];
    const float* bq = (const float*)d_in[3];
    const float* Wk = (const float*)d_in[4];
    const float* bk = (const float*)d_in[5];
    const float* Wv = (const float*)d_in[6];
    const float* bv = (const float*)d_in[7];
    const float* Wo = (const float*)d_in[8];
    const float* bo = (const float*)d_in[9];
    float* out = (float*)d_out;

    const size_t TEN = (size_t)MTOT * D_MODEL;
    const size_t WEL = (size_t)D_MODEL * D_MODEL;
    char* p = (char*)d_ws;
    u16* xb  = (u16*)p; p += TEN * 2;
    u16* wqb = (u16*)p; p += WEL * 2;
    u16* wkb = (u16*)p; p += WEL * 2;
    u16* wvb = (u16*)p; p += WEL * 2;
    u16* wob = (u16*)p; p += WEL * 2;
    u16* Qb  = (u16*)p; p += TEN * 2;
    u16* Kb  = (u16*)p; p += TEN * 2;
    u16* Vb  = (u16*)p; p += TEN * 2;   // transposed layout [B,H,Dh,S]
    u16* An  = (u16*)p; p += TEN * 2;
    float* tc = (float*)p; p += (size_t)SEQ * 64 * 4;
    float* ts = (float*)p;

    f2b_kernel<<<dim3(12288), 256, 0, stream>>>(x, Wq, Wk, Wv, Wo,
                                                xb, wqb, wkb, wvb, wob);
    rope_table<<<dim3(512), 256, 0, stream>>>(tc, ts);
    gemm_bf16<<<dim3(16, 32, 3), 256, 0, stream>>>(xb, wqb, wkb, wvb,
                                                   bq, bk, bv, Qb, Kb, Vb, 0);
    rope_apply<<<dim3(16384, 2), 256, 0, stream>>>(Qb, Kb, tc, ts);
    flash_attn_mfma<<<dim3(32, 32), 256, 0, stream>>>(Qb, Kb, Vb, An);
    gemm_bf16<<<dim3(16, 32, 1), 256, 0, stream>>>(An, wob, wob, wob,
                                                   bo, bo, bo, out, out, out, 1);
}

// Round 4
// 457.310 us; speedup vs baseline: 7.8286x; 1.4683x over previous
//
#include <hip/hip_runtime.h>
#include <math.h>

#define D_MODEL 2048
#define NHEADS  16
#define HDIM    128
#define BATCH   2
#define SEQ     2048
#define MTOT    (BATCH*SEQ)   // 4096

typedef unsigned short u16;
typedef unsigned int   u32;
typedef __attribute__((ext_vector_type(8))) short  short8;
typedef __attribute__((ext_vector_type(8))) u16    ushort8;
typedef __attribute__((ext_vector_type(4))) u16    us4;
typedef __attribute__((ext_vector_type(4))) float  floatx4;

__device__ __forceinline__ u16 f2b(float f) {          // fp32 -> bf16 RNE
    u32 u = __float_as_uint(f);
    return (u16)((u + 0x7fffu + ((u >> 16) & 1u)) >> 16);
}
__device__ __forceinline__ float b2f(u16 b) {          // bf16 -> fp32 exact
    return __uint_as_float(((u32)b) << 16);
}
__device__ __forceinline__ void async16(void* lds, const void* g) {
    __builtin_amdgcn_global_load_lds(
        (const __attribute__((address_space(1))) u32*)g,
        (__attribute__((address_space(3))) u32*)lds, 16, 0, 0);
}

// ---------------------------------------------------------------------------
// fp32 -> bf16 conversion for x and the 4 weight matrices.
// ---------------------------------------------------------------------------
__global__ __launch_bounds__(256)
void f2b_kernel(const float* __restrict__ x,
                const float* __restrict__ wq, const float* __restrict__ wk,
                const float* __restrict__ wv, const float* __restrict__ wo,
                u16* __restrict__ xb, u16* __restrict__ wqb, u16* __restrict__ wkb,
                u16* __restrict__ wvb, u16* __restrict__ wob)
{
    const int bid = blockIdx.x;
    const float* src; u16* dst; int lb;
    if (bid < 4096) { src = x; dst = xb; lb = bid; }
    else {
        const int t = (bid - 4096) >> 11;
        lb = (bid - 4096) & 2047;
        src = (t == 0) ? wq : (t == 1) ? wk : (t == 2) ? wv : wo;
        dst = (t == 0) ? wqb : (t == 1) ? wkb : (t == 2) ? wvb : wob;
    }
    const size_t e = ((size_t)lb * 256 + threadIdx.x) * 8;
    const float4 a = *(const float4*)&src[e];
    const float4 b = *(const float4*)&src[e + 4];
    union { u16 u[8]; uint4 v; } o;
    o.u[0] = f2b(a.x); o.u[1] = f2b(a.y); o.u[2] = f2b(a.z); o.u[3] = f2b(a.w);
    o.u[4] = f2b(b.x); o.u[5] = f2b(b.y); o.u[6] = f2b(b.z); o.u[7] = f2b(b.w);
    *(uint4*)&dst[e] = o.v;
}

// ---------------------------------------------------------------------------
// bf16 MFMA GEMM: C = A[M,2048] @ W[N,2048]^T + bias (fp32 accum).
// mode 0: z=0/1 write bf16 [B,H,S,Dh]; z=2 writes bf16 V TRANSPOSED [B,H,Dh,S].
// mode 1: plain fp32 [M,N].
// ---------------------------------------------------------------------------
__global__ __launch_bounds__(256)
void gemm_bf16(const u16* __restrict__ A,
               const u16* W0, const u16* W1, const u16* W2,
               const float* b0, const float* b1, const float* b2,
               void* C0, void* C1, void* C2, int mode)
{
    __shared__ __align__(16) u16 As[128 * 32];
    __shared__ __align__(16) u16 Bs[128 * 32];

    const int z = blockIdx.z;
    const u16*   W    = (z == 0) ? W0 : (z == 1) ? W1 : W2;
    const float* bias = (z == 0) ? b0 : (z == 1) ? b1 : b2;
    void*        C    = (z == 0) ? C0 : (z == 1) ? C1 : C2;

    const int tid  = threadIdx.x;
    const int lane = tid & 63;
    const int wv   = tid >> 6;
    const int wr   = wv >> 1, wc = wv & 1;
    const int m0 = blockIdx.y * 128, n0 = blockIdx.x * 128;

    floatx4 acc[4][4];
    #pragma unroll
    for (int i = 0; i < 4; ++i)
        #pragma unroll
        for (int j = 0; j < 4; ++j) acc[i][j] = (floatx4){0.f, 0.f, 0.f, 0.f};

    const int f0 = tid, f1 = tid + 256;
    const char* Ag = (const char*)(A + (size_t)m0 * 2048);
    const char* Wg = (const char*)(W + (size_t)n0 * 2048);
    const size_t a0 = (size_t)(f0 >> 2) * 4096 + (f0 & 3) * 16;
    const size_t a1 = (size_t)(f1 >> 2) * 4096 + (f1 & 3) * 16;

    const int lrow = lane & 15, lk = (lane >> 4) * 8;

    for (int k0 = 0; k0 < 2048; k0 += 32) {
        __syncthreads();
        const size_t kb = (size_t)k0 * 2;
        async16(&As[f0 * 8], Ag + a0 + kb);
        async16(&As[f1 * 8], Ag + a1 + kb);
        async16(&Bs[f0 * 8], Wg + a0 + kb);
        async16(&Bs[f1 * 8], Wg + a1 + kb);
        __syncthreads();

        short8 af[4], bf[4];
        #pragma unroll
        for (int i = 0; i < 4; ++i)
            af[i] = *(const short8*)&As[(wr * 64 + i * 16 + lrow) * 32 + lk];
        #pragma unroll
        for (int j = 0; j < 4; ++j)
            bf[j] = *(const short8*)&Bs[(wc * 64 + j * 16 + lrow) * 32 + lk];
        #pragma unroll
        for (int i = 0; i < 4; ++i)
            #pragma unroll
            for (int j = 0; j < 4; ++j)
                acc[i][j] = __builtin_amdgcn_mfma_f32_16x16x32_bf16(af[i], bf[j], acc[i][j], 0, 0, 0);
    }

    float bb[4];
    #pragma unroll
    for (int j = 0; j < 4; ++j) bb[j] = bias[n0 + wc * 64 + j * 16 + lrow];

    #pragma unroll
    for (int i = 0; i < 4; ++i) {
        #pragma unroll
        for (int j = 0; j < 4; ++j) {
            const int col  = n0 + wc * 64 + j * 16 + lrow;
            const int row0 = m0 + wr * 64 + i * 16 + (lane >> 4) * 4;
            if (mode == 0) {
                const int b = row0 >> 11, s = row0 & (SEQ - 1);
                const int h = col >> 7,  d = col & 127;
                if (z == 2) {
                    us4 pk;
                    #pragma unroll
                    for (int q = 0; q < 4; ++q) pk[q] = f2b(acc[i][j][q] + bb[j]);
                    *(us4*)&((u16*)C)[(((size_t)(b * NHEADS + h)) * HDIM + d) * SEQ + s] = pk;
                } else {
                    #pragma unroll
                    for (int q = 0; q < 4; ++q)
                        ((u16*)C)[(((size_t)(b * NHEADS + h)) * SEQ + s + q) * HDIM + d]
                            = f2b(acc[i][j][q] + bb[j]);
                }
            } else {
                #pragma unroll
                for (int q = 0; q < 4; ++q)
                    ((float*)C)[(size_t)(row0 + q) * D_MODEL + col] = acc[i][j][q] + bb[j];
            }
        }
    }
}

// ---------------------------------------------------------------------------
// RoPE table + apply. Q is additionally pre-scaled by 1/sqrt(HDIM).
// ---------------------------------------------------------------------------
__global__ void rope_table(float* __restrict__ tcos, float* __restrict__ tsin)
{
    const int idx = blockIdx.x * 256 + threadIdx.x;   // SEQ*64
    const int s = idx >> 6, i = idx & 63;
    const float inv = powf(10000.0f, -(float)i / 64.0f);
    const float ang = (float)s * inv;
    tcos[idx] = cosf(ang);
    tsin[idx] = sinf(ang);
}

__global__ void rope_apply(u16* __restrict__ Q, u16* __restrict__ K,
                           const float* __restrict__ tcos, const float* __restrict__ tsin)
{
    const int idx = blockIdx.x * 256 + threadIdx.x;
    u16* P = blockIdx.y ? K : Q;
    const float sc = blockIdx.y ? 1.0f : 0.08838834764831845f;  // 1/sqrt(128)
    const int i   = idx & 63;
    const int bhs = idx >> 6;
    const int s   = bhs & (SEQ - 1);
    const size_t base = (size_t)bhs * HDIM;
    const float x1 = b2f(P[base + i]), x2 = b2f(P[base + i + 64]);
    const float c  = tcos[(s << 6) + i], sn = tsin[(s << 6) + i];
    P[base + i]      = f2b((x1 * c  - x2 * sn) * sc);
    P[base + i + 64] = f2b((x1 * sn + x2 * c) * sc);
}

// ---------------------------------------------------------------------------
// MFMA flash attention v2.
// Block = (b,h) x 128 q-rows; 4 waves x 32 q-rows. KV tile = 64.
// Swapped QK^T: s = mfma(K,Q) -> P-row in-lane (col=q=lane&15, row=kv).
// Double-buffered K/V staging: prefetch tile t+1 before computing tile t;
// single __syncthreads per tile drains it after the compute phase.
// qt descending in blockIdx.x => heaviest blocks dispatch first (LPT).
// ---------------------------------------------------------------------------
__global__ __launch_bounds__(256, 2)
void flash_attn_mfma(const u16* __restrict__ Q, const u16* __restrict__ K,
                     const u16* __restrict__ Vt, u16* __restrict__ O)
{
    __shared__ __align__(16) u16 Ks[2][64 * 128];   // 2 x 16 KB
    __shared__ __align__(16) u16 Vs[2][128 * 64];   // 2 x 16 KB
    __shared__ __align__(16) u16 Ps[128 * 64];      // 16 KB  -> 80 KB total

    const int tid = threadIdx.x, lane = tid & 63, w = tid >> 6;
    const int l15 = lane & 15, l4 = lane >> 4;
    const int bh = blockIdx.y;
    const int qt = 15 - blockIdx.x;                 // descending workload
    const int q0 = qt * 128;
    const int qw = q0 + w * 32;                     // wave's 32 q rows
    const size_t baseQK = (size_t)bh * SEQ * HDIM;
    const size_t baseV  = (size_t)bh * HDIM * SEQ;

    // ---- Q fragments from global (rope'd + pre-scaled). B-operand layout ----
    short8 qf[2][4];
    #pragma unroll
    for (int u = 0; u < 2; ++u) {
        const u16* Qg = Q + baseQK + (size_t)(qw + u * 16 + l15) * HDIM;
        #pragma unroll
        for (int kk = 0; kk < 4; ++kk) qf[u][kk] = *(const short8*)&Qg[kk * 32 + l4 * 8];
    }

    floatx4 o_acc[2][8];
    #pragma unroll
    for (int u = 0; u < 2; ++u)
        #pragma unroll
        for (int j2 = 0; j2 < 8; ++j2) o_acc[u][j2] = (floatx4){0.f, 0.f, 0.f, 0.f};
    float m_run[2] = {-INFINITY, -INFINITY}, l_run[2] = {0.f, 0.f};

    const int nt = 2 * qt + 2;

    // ---- staging helper (inverse-swizzled global source, linear LDS) ----
    #define STAGE(buf, k0_)                                                     \
    {                                                                           \
        const u16* Kg = K  + baseQK + (size_t)(k0_) * HDIM;                     \
        const u16* Vg = Vt + baseV  + (k0_);                                    \
        _Pragma("unroll")                                                       \
        for (int p_ = 0; p_ < 4; ++p_) {                                        \
            const int idx = p_ * 256 + tid;                                     \
            const int r_ = idx >> 4, c_ = idx & 15;                             \
            const int srcK = (c_ & 8) | ((c_ & 7) ^ (r_ & 7));                  \
            async16(&Ks[buf][idx * 8], Kg + r_ * HDIM + srcK * 8);              \
            const int rv = idx >> 3, cv = idx & 7;                              \
            const int srcV = cv ^ (rv & 7);                                     \
            async16(&Vs[buf][idx * 8], Vg + (size_t)rv * SEQ + srcV * 8);       \
        }                                                                       \
    }

    STAGE(0, 0);
    __syncthreads();                     // drains vmcnt(0), barrier
    int cur = 0;

    for (int t = 0; t < nt; ++t) {
        if (t + 1 < nt) STAGE(cur ^ 1, (t + 1) * 64);

        // ---- QK^T (swapped): s[u][j] = K_j * Q_u ; lane: q=l15, kv=l4*4+r ----
        floatx4 s[2][4];
        #pragma unroll
        for (int u = 0; u < 2; ++u)
            #pragma unroll
            for (int j = 0; j < 4; ++j) s[u][j] = (floatx4){0.f, 0.f, 0.f, 0.f};
        #pragma unroll
        for (int j = 0; j < 4; ++j) {
            const int row = j * 16 + l15;
            #pragma unroll
            for (int kk = 0; kk < 4; ++kk) {
                const int x  = kk * 4 + l4;
                const int ch = (x & 8) | ((x & 7) ^ (row & 7));
                const short8 kf = *(const short8*)&Ks[cur][row * 128 + ch * 8];
                s[0][j] = __builtin_amdgcn_mfma_f32_16x16x32_bf16(kf, qf[0][kk], s[0][j], 0, 0, 0);
                s[1][j] = __builtin_amdgcn_mfma_f32_16x16x32_bf16(kf, qf[1][kk], s[1][j], 0, 0, 0);
            }
        }

        // ---- causal mask (last two tiles only) ----
        if (t >= nt - 2) {
            const int k0 = t * 64;
            #pragma unroll
            for (int u = 0; u < 2; ++u) {
                const int qg = qw + u * 16 + l15;
                #pragma unroll
                for (int j = 0; j < 4; ++j)
                    #pragma unroll
                    for (int r = 0; r < 4; ++r)
                        if (k0 + j * 16 + l4 * 4 + r > qg) s[u][j][r] = -INFINITY;
            }
        }

        // ---- online softmax: in-lane tree + 2 shuffles; P -> LDS (8B) ----
        float al[2];
        #pragma unroll
        for (int u = 0; u < 2; ++u) {
            float m0_ = fmaxf(fmaxf(s[u][0][0], s[u][0][1]), fmaxf(s[u][0][2], s[u][0][3]));
            float m1_ = fmaxf(fmaxf(s[u][1][0], s[u][1][1]), fmaxf(s[u][1][2], s[u][1][3]));
            float m2_ = fmaxf(fmaxf(s[u][2][0], s[u][2][1]), fmaxf(s[u][2][2], s[u][2][3]));
            float m3_ = fmaxf(fmaxf(s[u][3][0], s[u][3][1]), fmaxf(s[u][3][2], s[u][3][3]));
            float mt = fmaxf(fmaxf(m0_, m1_), fmaxf(m2_, m3_));
            mt = fmaxf(mt, __shfl_xor(mt, 16));
            mt = fmaxf(mt, __shfl_xor(mt, 32));
            const float mn = fmaxf(m_run[u], mt);
            al[u] = __expf(m_run[u] - mn);
            m_run[u] = mn;
            const int prow = w * 32 + u * 16 + l15;
            const int swz  = (prow & 7) << 3;
            float rs = 0.f;
            #pragma unroll
            for (int j = 0; j < 4; ++j) {
                float p0 = __expf(s[u][j][0] - mn), p1 = __expf(s[u][j][1] - mn);
                float p2 = __expf(s[u][j][2] - mn), p3 = __expf(s[u][j][3] - mn);
                rs += (p0 + p1) + (p2 + p3);
                us4 pk; pk[0] = f2b(p0); pk[1] = f2b(p1); pk[2] = f2b(p2); pk[3] = f2b(p3);
                *(us4*)&Ps[prow * 64 + ((j * 16 + l4 * 4) ^ swz)] = pk;
            }
            rs += __shfl_xor(rs, 16);
            rs += __shfl_xor(rs, 32);
            l_run[u] = l_run[u] * al[u] + rs;
        }

        // ---- rescale o_acc (al redistributed: o rows are q = l4*4+r) ----
        #pragma unroll
        for (int u = 0; u < 2; ++u) {
            float alr[4];
            #pragma unroll
            for (int r = 0; r < 4; ++r) alr[r] = __shfl(al[u], l4 * 4 + r, 16);
            #pragma unroll
            for (int j2 = 0; j2 < 8; ++j2)
                #pragma unroll
                for (int r = 0; r < 4; ++r) o_acc[u][j2][r] *= alr[r];
        }

        // ---- PV: o[u][j2] += P_u * V_j2  (A=pf row=q, k=kv; B=vf row=d) ----
        #pragma unroll
        for (int ks = 0; ks < 2; ++ks) {
            short8 pf[2];
            #pragma unroll
            for (int u = 0; u < 2; ++u) {
                const int prow = w * 32 + u * 16 + l15;
                pf[u] = *(const short8*)&Ps[prow * 64 + ((ks * 32 + l4 * 8) ^ ((prow & 7) << 3))];
            }
            #pragma unroll
            for (int j2 = 0; j2 < 8; ++j2) {
                const int vrow = j2 * 16 + l15;
                const int vch  = (ks * 4 + l4) ^ (vrow & 7);
                const short8 vf = *(const short8*)&Vs[cur][vrow * 64 + vch * 8];
                o_acc[0][j2] = __builtin_amdgcn_mfma_f32_16x16x32_bf16(pf[0], vf, o_acc[0][j2], 0, 0, 0);
                o_acc[1][j2] = __builtin_amdgcn_mfma_f32_16x16x32_bf16(pf[1], vf, o_acc[1][j2], 0, 0, 0);
            }
        }

        __syncthreads();                 // drains prefetch vmcnt(0) + buf reuse
        cur ^= 1;
    }

    // ---- epilogue: normalize (inv redistributed like al), write bf16 ----
    const int b = bh >> 4, h = bh & 15;
    #pragma unroll
    for (int u = 0; u < 2; ++u) {
        const float invl = 1.f / l_run[u];
        float invr[4];
        #pragma unroll
        for (int r = 0; r < 4; ++r) invr[r] = __shfl(invl, l4 * 4 + r, 16);
        #pragma unroll
        for (int r = 0; r < 4; ++r) {
            const int s_ = qw + u * 16 + l4 * 4 + r;
            u16* dst = O + ((size_t)b * SEQ + s_) * D_MODEL + h * HDIM;
            #pragma unroll
            for (int j2 = 0; j2 < 8; ++j2)
                dst[j2 * 16 + l15] = f2b(o_acc[u][j2][r] * invr[r]);
        }
    }
    #undef STAGE
}

// ---------------------------------------------------------------------------
extern "C" void kernel_launch(void* const* d_in, const int* in_sizes, int n_in,
                              void* d_out, int out_size, void* d_ws, size_t ws_size,
                              hipStream_t stream)
{
    const float* x  = (const float*)d_in[0];
    const float* Wq = (const float*)d_in[2];
    const float* bq = (const float*)d_in[3];
    const float* Wk = (const float*)d_in[4];
    const float* bk = (const float*)d_in[5];
    const float* Wv = (const float*)d_in[6];
    const float* bv = (const float*)d_in[7];
    const float* Wo = (const float*)d_in[8];
    const float* bo = (const float*)d_in[9];
    float* out = (float*)d_out;

    const size_t TEN = (size_t)MTOT * D_MODEL;
    const size_t WEL = (size_t)D_MODEL * D_MODEL;
    char* p = (char*)d_ws;
    u16* xb  = (u16*)p; p += TEN * 2;
    u16* wqb = (u16*)p; p += WEL * 2;
    u16* wkb = (u16*)p; p += WEL * 2;
    u16* wvb = (u16*)p; p += WEL * 2;
    u16* wob = (u16*)p; p += WEL * 2;
    u16* Qb  = (u16*)p; p += TEN * 2;
    u16* Kb  = (u16*)p; p += TEN * 2;
    u16* Vb  = (u16*)p; p += TEN * 2;   // transposed layout [B,H,Dh,S]
    u16* An  = (u16*)p; p += TEN * 2;
    float* tc = (float*)p; p += (size_t)SEQ * 64 * 4;
    float* ts = (float*)p;

    f2b_kernel<<<dim3(12288), 256, 0, stream>>>(x, Wq, Wk, Wv, Wo,
                                                xb, wqb, wkb, wvb, wob);
    rope_table<<<dim3(512), 256, 0, stream>>>(tc, ts);
    gemm_bf16<<<dim3(16, 32, 3), 256, 0, stream>>>(xb, wqb, wkb, wvb,
                                                   bq, bk, bv, Qb, Kb, Vb, 0);
    rope_apply<<<dim3(16384, 2), 256, 0, stream>>>(Qb, Kb, tc, ts);
    flash_attn_mfma<<<dim3(16, 32), 256, 0, stream>>>(Qb, Kb, Vb, An);
    gemm_bf16<<<dim3(16, 32, 1), 256, 0, stream>>>(An, wob, wob, wob,
                                                   bo, bo, bo, out, out, out, 1);
}